// Round 13
// baseline (18.548 us; speedup 1.0000x reference)
//
#include <hip/hip_runtime.h>

typedef __attribute__((ext_vector_type(8))) _Float16 half8;
typedef __attribute__((ext_vector_type(2))) _Float16 half2v;
typedef __attribute__((ext_vector_type(4))) float f32x4;

namespace {
constexpr int kB = 2048;
constexpr int kF = 64;
constexpr int kC = 10;
constexpr int kS = 5;
constexpr int kG = kC + kS;          // 15 groups
constexpr int kH1 = 32;
constexpr int kH2 = 16;
constexpr float kWCat = 0.7f / kC;
constexpr float kWSub = 0.3f / kS;
constexpr int kThreads = 512;        // 8 waves
constexpr int kRowsPerBlock = 256;   // 8 waves x 2 tiles x 16 rows
constexpr int kChunks = kB / kRowsPerBlock;   // 8 -> grid = 64*8 = 512

// Compact record: 320 floats per (f,g), f-major:
//   [0..31]    w1b1 f16: u16 slot kg*16+j = w1[kg*8+j], kg*16+8+j = b1[kg*8+j]
//   [32..287]  B-fragment (W2^T): lane l -> half8 at float offset 32+4*l
//   [288..319] per kg: [kg*8 +0..3]=b2 quad (f32), [kg*8+4..7]=w3*wgt quad
// Per f: 15 records (4800 floats) + bsum at [4800]; stride 4864 floats.
constexpr int kRecF = 320;
constexpr int kFStride = 4864;
constexpr int kStageF4 = 1201;       // (4800+4)/4 float4s staged
}

// Node 1: pack weights into fragment-ready records. 240 blocks x 4 waves,
// one wave per (g,f) record; every weight byte read from HBM once, coalesced.
// g==0 waves also compute bsum[f]; blocks 0..7 zero out[].
__global__ __launch_bounds__(256) void pack_kernel(
    const float* __restrict__ cW1, const float* __restrict__ cB1,
    const float* __restrict__ cW2, const float* __restrict__ cB2,
    const float* __restrict__ cW3, const float* __restrict__ cB3,
    const float* __restrict__ cbias,
    const float* __restrict__ sW1, const float* __restrict__ sB1,
    const float* __restrict__ sW2, const float* __restrict__ sB2,
    const float* __restrict__ sW3, const float* __restrict__ sB3,
    const float* __restrict__ sbias,
    float* __restrict__ wsPack, float* __restrict__ out) {
    const int tid = threadIdx.x;
    if (blockIdx.x < 8) out[blockIdx.x * 256 + tid] = 0.f;

    const int rec_id = blockIdx.x * 4 + (tid >> 6);   // 0..959
    const int g = rec_id >> 6, f = rec_id & (kF - 1);
    const int l = tid & 63;

    const float *W1, *B1, *W2, *B2, *W3, *B3; float wgt; int base;
    if (g < kC) {
        base = g * kF + f;
        W1 = cW1; B1 = cB1; W2 = cW2; B2 = cB2; W3 = cW3; B3 = cB3; wgt = kWCat;
    } else {
        base = (g - kC) * kF + f;
        W1 = sW1; B1 = sB1; W2 = sW2; B2 = sB2; W3 = sW3; B3 = sB3; wgt = kWSub;
    }
    float* rec = wsPack + (size_t)f * kFStride + g * kRecF;
    unsigned short* rec16 = (unsigned short*)rec;

    // B-fragment: lane l -> fp16(W2[k=(l>>4)*8+j][n=l&15]), j=0..7.
    const float* w2p = W2 + (size_t)base * (kH1 * kH2) + ((l >> 4) * 8) * kH2 + (l & 15);
    half8 bw;
    #pragma unroll
    for (int j = 0; j < 8; ++j) bw[j] = (_Float16)w2p[j * kH2];
    *(half8*)(rec + 32 + 4 * l) = bw;

    // w1/b1 as f16.
    if (l < kH1) {
        const int kgw = l >> 3, j = l & 7;
        rec16[kgw * 16 + j]     = __builtin_bit_cast(unsigned short,
                                      (_Float16)W1[(size_t)base * kH1 + l]);
        rec16[kgw * 16 + 8 + j] = __builtin_bit_cast(unsigned short,
                                      (_Float16)B1[(size_t)base * kH1 + l]);
    }
    // b2 / w3*wgt quads, indexed by row n = kg*4 + r.
    if (l < kH2) {
        rec[288 + (l >> 2) * 8 + (l & 3)]     = B2[(size_t)base * kH2 + l];
        rec[288 + (l >> 2) * 8 + 4 + (l & 3)] = W3[(size_t)base * kH2 + l] * wgt;
    }
    // bsum[f]: only the g==0 wave computes it.
    if (g == 0) {
        float v = 0.f;
        if (l < kC)            v = kWCat * cB3[l * kF + f];
        else if (l < kG)       v = kWSub * sB3[(l - kC) * kF + f];
        v += __shfl_xor(v, 1);
        v += __shfl_xor(v, 2);
        v += __shfl_xor(v, 4);
        v += __shfl_xor(v, 8);
        if (l == 0) {
            if (f == 0) {
                #pragma unroll
                for (int i = 0; i < kC; ++i) v = fmaf(cbias[i], kWCat, v);
                #pragma unroll
                for (int i = 0; i < kS; ++i) v = fmaf(sbias[i], kWSub, v);
            }
            wsPack[(size_t)f * kFStride + 4800] = v;
        }
    }
}

// Node 2: one block per (f, 256-row chunk): 512 blocks x 8 waves (2/CU).
// One 19.2 KB stage serves 8 waves x 2 tiles. Transposed-MFMA group loop;
// single 32-lane atomicAdd per wave-tile-pair into out.
__global__ __launch_bounds__(kThreads, 4) void nam_packed(
    const float* __restrict__ x, const float* __restrict__ wsPack,
    float* __restrict__ out) {
    const int f     = blockIdx.x & (kF - 1);
    const int chunk = blockIdx.x >> 6;
    const int tid   = threadIdx.x;

    __shared__ float4 ldsv[kStageF4];   // 19216 B
    const float4* src = (const float4*)(wsPack + (size_t)f * kFStride);
    #pragma unroll
    for (int r = 0; r < 3; ++r) {
        const int idx = tid + r * kThreads;
        if (idx < kStageF4) ldsv[idx] = src[idx];
    }
    __syncthreads();
    const float* lds = (const float*)ldsv;

    const int wave = tid >> 6;
    const int lane = tid & 63;
    const int n  = lane & 15;    // batch column b in the transposed product
    const int kg = lane >> 4;
    const int rowbase = chunk * kRowsPerBlock + wave * 32;

    half2v xh[2];
    #pragma unroll
    for (int t = 0; t < 2; ++t) {
        const _Float16 v = (_Float16)x[(size_t)(rowbase + t * 16 + n) * kF + f];
        xh[t][0] = v; xh[t][1] = v;
    }

    float acc0 = 0.f, acc1 = 0.f;
    const half2v hz = { (_Float16)0.f, (_Float16)0.f };

    #pragma unroll 3
    for (int g = 0; g < kG; ++g) {
        const float* rec = lds + g * kRecF;
        const half8 w1h = *(const half8*)(rec + kg * 8);       // w1 j=0..7
        const half8 b1h = *(const half8*)(rec + kg * 8 + 4);   // b1 j=0..7
        const half8 bw  = *(const half8*)(rec + 32 + 4 * lane);
        const f32x4 b2q = *(const f32x4*)(rec + 288 + kg * 8);
        const f32x4 w3q = *(const f32x4*)(rec + 288 + kg * 8 + 4);

        const half2v w01 = { w1h[0], w1h[1] }, w23 = { w1h[2], w1h[3] };
        const half2v w45 = { w1h[4], w1h[5] }, w67 = { w1h[6], w1h[7] };
        const half2v b01 = { b1h[0], b1h[1] }, b23 = { b1h[2], b1h[3] };
        const half2v b45 = { b1h[4], b1h[5] }, b67 = { b1h[6], b1h[7] };

        #pragma unroll
        for (int t = 0; t < 2; ++t) {
            half2v p0 = __builtin_elementwise_max(
                __builtin_elementwise_fma(xh[t], w01, b01), hz);
            half2v p1 = __builtin_elementwise_max(
                __builtin_elementwise_fma(xh[t], w23, b23), hz);
            half2v p2 = __builtin_elementwise_max(
                __builtin_elementwise_fma(xh[t], w45, b45), hz);
            half2v p3 = __builtin_elementwise_max(
                __builtin_elementwise_fma(xh[t], w67, b67), hz);
            half8 aw;
            aw[0] = p0[0]; aw[1] = p0[1];
            aw[2] = p1[0]; aw[3] = p1[1];
            aw[4] = p2[0]; aw[5] = p2[1];
            aw[6] = p3[0]; aw[7] = p3[1];
            // Transposed: D = W2^T * h1^T; col = lane&15 = b, row = kg*4+r = n.
            f32x4 c = __builtin_amdgcn_mfma_f32_16x16x32_f16(bw, aw, b2q, 0, 0, 0);
            float p = fmaxf(c[0], 0.f) * w3q[0];
            p = fmaf(fmaxf(c[1], 0.f), w3q[1], p);
            p = fmaf(fmaxf(c[2], 0.f), w3q[2], p);
            p = fmaf(fmaxf(c[3], 0.f), w3q[3], p);
            if (t == 0) acc0 += p; else acc1 += p;
        }
    }

    // Reduce over the 16 h2-columns; lanes 0-15 carry t0, 16-31 carry t1:
    // one 32-lane atomic instruction per wave.
    acc0 += __shfl_xor(acc0, 16); acc0 += __shfl_xor(acc0, 32);
    acc1 += __shfl_xor(acc1, 16); acc1 += __shfl_xor(acc1, 32);
    const float bsum = lds[4800];
    const float v = (lane & 16) ? acc1 : acc0;
    if (lane < 32)
        atomicAdd(&out[rowbase + (lane & 16) + n], v + bsum);
}

extern "C" void kernel_launch(void* const* d_in, const int* in_sizes, int n_in,
                              void* d_out, int out_size, void* d_ws, size_t ws_size,
                              hipStream_t stream) {
    const float* x     = (const float*)d_in[0];
    const float* cW1   = (const float*)d_in[1];
    const float* cB1   = (const float*)d_in[2];
    const float* cW2   = (const float*)d_in[3];
    const float* cB2   = (const float*)d_in[4];
    const float* cW3   = (const float*)d_in[5];
    const float* cB3   = (const float*)d_in[6];
    const float* cbias = (const float*)d_in[7];
    const float* sW1   = (const float*)d_in[8];
    const float* sB1   = (const float*)d_in[9];
    const float* sW2   = (const float*)d_in[10];
    const float* sB2   = (const float*)d_in[11];
    const float* sW3   = (const float*)d_in[12];
    const float* sB3   = (const float*)d_in[13];
    const float* sbias = (const float*)d_in[14];
    float* out = (float*)d_out;
    float* wsPack = (float*)d_ws;     // 64*4864 floats = 1.24 MB
    (void)ws_size; (void)n_in; (void)in_sizes; (void)out_size;

    pack_kernel<<<kG * kF / 4, 256, 0, stream>>>(cW1, cB1, cW2, cB2, cW3, cB3, cbias,
                                                 sW1, sB1, sW2, sB2, sW3, sB3, sbias,
                                                 wsPack, out);
    nam_packed<<<kF * kChunks, kThreads, 0, stream>>>(x, wsPack, out);
}